// Round 10
// baseline (436.837 us; speedup 1.0000x reference)
//
#include <hip/hip_runtime.h>
#include <float.h>
#include <math.h>

#define NSAMP 100
#define IMG_W 2048
#define IMG_H 2048
#define SEG 25          // centers per segment (R5/R8-verified decomposition)
#define NSEG 4          // segments per point
#define NREG 8          // image regions = XCDs; tiles 512 wide x 1024 tall (4x2)

typedef _Float16 h2_t __attribute__((ext_vector_type(2), aligned(4)));
typedef _Float16 h4_t __attribute__((ext_vector_type(4), aligned(8)));
typedef _Float16 h8_t __attribute__((ext_vector_type(8), aligned(16)));

__device__ __forceinline__ float tparam(int s) {
    // matches np.linspace(0,1,100), bitwise-verified rounds 1-9
    return (s == NSAMP - 1) ? 1.0f : (float)((double)s * (1.0 / 99.0));
}

// Chord setup shared by bin and main (bitwise-identical formulas, R8-verified).
__device__ __forceinline__ void chord(float px, float py, float nx, float ny,
                                      float& p1x, float& p1y, float& vx, float& vy) {
    float ddx = -ny, ddy = nx;
    float nrm = sqrtf(ddx * ddx + ddy * ddy);
    float dx = ddx / nrm, dy = ddy / nrm;
    const float maxf = FLT_MAX;
    float sdx = (dx != 0.f) ? dx : 1.f;
    float sdy = (dy != 0.f) ? dy : 1.f;
    float t_left   = (dx != 0.f) ? (0.f    - px) / sdx : -maxf;
    float t_right  = (dx != 0.f) ? (2047.f - px) / sdx :  maxf;
    float t_top    = (dy != 0.f) ? (0.f    - py) / sdy : -maxf;
    float t_bottom = (dy != 0.f) ? (2047.f - py) / sdy :  maxf;
    float t_min = fmaxf(t_left, t_top);
    float t_max = fminf(t_right, t_bottom);
    p1x = px + t_min * dx; p1y = py + t_min * dy;
    float p2x = px + t_max * dx, p2y = py + t_max * dy;
    vx = p2x - p1x; vy = p2y - p1y;
}

// ---------- fused: V-texture build (R7-verified) + point binning (R8-verified) ----------
__global__ __launch_bounds__(256) void convert_bin_kernel(
        const float* __restrict__ in, h2_t* __restrict__ V,
        const float* __restrict__ points, const float* __restrict__ normals,
        float4* __restrict__ pts4, unsigned int* __restrict__ regs,
        unsigned int* __restrict__ qcnt,
        double* __restrict__ accum, unsigned int* __restrict__ done,
        int N) {
    __shared__ unsigned int lh[NREG];
    if (threadIdx.x < NREG) lh[threadIdx.x] = 0u;
    __syncthreads();
    int idx = blockIdx.x * blockDim.x + threadIdx.x;   // 1M threads
    if (idx == 0) { *accum = 0.0; *done = 0u; }
    if (idx < NREG) qcnt[idx] = 0u;    // zeroed before any atomicAdd below? no --
    // NOTE: qcnt zeroing must not race with other blocks' atomics. Since the
    // harness poisons d_ws each call, zero qcnt here only via block 0 is racy.
    // Instead qcnt is NOT zeroed here; it is accumulated into per-block lh and
    // flushed AFTER a device-side zero done in this same kernel would race.
    // -> handled by having bin atomics target qcnt_raw offset by +NREG below.

    // texture build
    {
        int y  = idx >> 9;          // row 0..2047
        int x4 = (idx & 511) << 2;  // col 0,4,..,2044
        int y1 = min(y + 1, IMG_H - 1);
        float4 a = *(const float4*)(in + (size_t)y  * IMG_W + x4);
        float4 b = *(const float4*)(in + (size_t)y1 * IMG_W + x4);
        h8_t o;
        o[0] = (_Float16)a.x; o[1] = (_Float16)b.x;
        o[2] = (_Float16)a.y; o[3] = (_Float16)b.y;
        o[4] = (_Float16)a.z; o[5] = (_Float16)b.z;
        o[6] = (_Float16)a.w; o[7] = (_Float16)b.w;
        *(h8_t*)(V + (size_t)y * IMG_W + x4) = o;
    }

    // point binning (first N threads)
    if (idx < N) {
        float px = fminf(fmaxf(points[2 * idx],     0.f), 2047.f);
        float py = fminf(fmaxf(points[2 * idx + 1], 0.f), 2047.f);
        float nx = normals[2 * idx];
        float ny = normals[2 * idx + 1];
        pts4[idx] = make_float4(px, py, nx, ny);
        float p1x, p1y, vx, vy;
        chord(px, py, nx, ny, p1x, p1y, vx, vy);
        unsigned int packed = 0;
        #pragma unroll
        for (int seg = 0; seg < NSEG; ++seg) {
            int s_begin = SEG * seg;
            int s_end   = min(s_begin + SEG + 1, NSAMP - 1);
            float f = (float)(s_begin + s_end) * 0.5f / 99.0f;
            float mx = fminf(fmaxf(p1x + f * vx, 0.f), 2047.f);
            float my = fminf(fmaxf(p1y + f * vy, 0.f), 2047.f);
            unsigned int r = ((unsigned int)my >> 10) * 4u + ((unsigned int)mx >> 9);
            packed |= r << (8 * seg);
            atomicAdd(&lh[r], 1u);
        }
        regs[idx] = packed;
    }
    __syncthreads();
    // flush per-block histogram with atomics into qcnt (qcnt zeroed by idx<NREG
    // path above -- but that races with other blocks' flushes!). Safe scheme:
    // qcnt zero happens in block that owns idx<NREG ONLY if that block also
    // flushes last... instead: qcnt is accumulated via atomics and the scan
    // kernel reads qcnt; zero-before-accumulate is done by having EVERY use of
    // qcnt go through scan which subtracts nothing. To make this robust under
    // the 0xAA poison, atomics must start from 0 -> we zero qcnt in a 1-block
    // prologue kernel instead (see kernel_launch).
    if (threadIdx.x < NREG && lh[threadIdx.x]) atomicAdd(&qcnt[threadIdx.x], lh[threadIdx.x]);
}

// tiny prologue: zero the 8 qcnt counters before convert_bin's atomics
__global__ void zero_qcnt_kernel(unsigned int* __restrict__ qcnt) {
    if (threadIdx.x < NREG) qcnt[threadIdx.x] = 0u;
}

// ---------- scan: region offsets + scatter cursors + qhead init ----------
__global__ void scan_kernel(const unsigned int* __restrict__ qcnt,
                            unsigned int* __restrict__ segoff,
                            unsigned int* __restrict__ cursor,
                            unsigned int* __restrict__ qhead) {
    if (threadIdx.x == 0) {
        unsigned int run = 0;
        for (int r = 0; r < NREG; ++r) {
            segoff[r] = run;
            cursor[r] = run;
            qhead[r]  = 0u;
            run += qcnt[r];
        }
    }
}

// ---------- scatter: block-aggregated placement (R8-verified) ----------
__global__ __launch_bounds__(256) void scatter_kernel(const unsigned int* __restrict__ regs,
                                                      unsigned int* __restrict__ cursor,
                                                      unsigned int* __restrict__ seglist,
                                                      int N) {
    __shared__ unsigned int lh[NREG];
    __shared__ unsigned int lbase[NREG];
    if (threadIdx.x < NREG) lh[threadIdx.x] = 0u;
    __syncthreads();
    int i = blockIdx.x * blockDim.x + threadIdx.x;
    unsigned int packed = 0, rank[NSEG];
    if (i < N) {
        packed = regs[i];
        #pragma unroll
        for (int seg = 0; seg < NSEG; ++seg) {
            unsigned int r = (packed >> (8 * seg)) & 0xFFu;
            rank[seg] = atomicAdd(&lh[r], 1u);
        }
    }
    __syncthreads();
    if (threadIdx.x < NREG)
        lbase[threadIdx.x] = lh[threadIdx.x] ? atomicAdd(&cursor[threadIdx.x], lh[threadIdx.x]) : 0u;
    __syncthreads();
    if (i < N) {
        #pragma unroll
        for (int seg = 0; seg < NSEG; ++seg) {
            unsigned int r = (packed >> (8 * seg)) & 0xFFu;
            seglist[lbase[r] + rank[seg]] = (unsigned int)(i * 4 + seg);
        }
    }
}

// ---------- bilinear via ONE 8-byte load (R7-verified) ----------
__device__ __forceinline__ float bilinV(const h2_t* __restrict__ V, float x, float y) {
    float x0f = floorf(x), y0f = floorf(y);
    float wx = x - x0f, wy = y - y0f;
    int x0 = (int)x0f;
    int y0 = (int)y0f;
    int xa = min(x0, IMG_W - 2);
    bool edge = (x0 == IMG_W - 1);
    h4_t q = *(const h4_t*)(V + (size_t)y0 * IMG_W + xa);
    float v00 = edge ? (float)q[2] : (float)q[0];
    float v10 = edge ? (float)q[3] : (float)q[1];
    float v01 = (float)q[2];
    float v11 = (float)q[3];
    return v00 * (1.f - wx) * (1.f - wy) + v01 * wx * (1.f - wy)
         + v10 * (1.f - wx) * wy       + v11 * wx * wy;
}

// ---------- main: XCD-home wave-popped queues, no barriers ----------
__global__ __launch_bounds__(256) void contour_seg_kernel(
        const h2_t* __restrict__ V,
        const float4* __restrict__ pts4,
        const unsigned int* __restrict__ seglist,
        const unsigned int* __restrict__ segoff,
        const unsigned int* __restrict__ qcnt,
        unsigned int* __restrict__ qhead,
        float4* __restrict__ rec) {
    unsigned int xcc;
    asm volatile("s_getreg_b32 %0, hwreg(HW_REG_XCC_ID)" : "=s"(xcc));
    xcc &= 7u;
    int lane = threadIdx.x & 63;

    for (int pass = 0; pass < NREG; ++pass) {
        unsigned int q = (xcc + (unsigned int)pass) & 7u;
        unsigned int qn = qcnt[q];
        unsigned int qo = segoff[q];
        while (true) {
            // cheap pre-check on non-home passes: skip drained queues w/o atomic
            if (pass > 0 && *(volatile const unsigned int*)&qhead[q] >= qn) break;
            unsigned int c = 0;
            if (lane == 0) c = atomicAdd(&qhead[q], 64u);
            c = __shfl(c, 0);
            if (c >= qn) break;
            unsigned int j = c + (unsigned int)lane;
            if (j < qn) {
                unsigned int e = seglist[qo + j];
                int i   = (int)(e >> 2);
                int seg = (int)(e & 3u);
                float4 pt = pts4[i];
                float px = pt.x, py = pt.y;
                float p1x, p1y, vx, vy;
                chord(px, py, pt.z, pt.w, p1x, p1y, vx, vy);

                float ref_val = 0.f;
                if (seg == 0) ref_val = bilinV(V, px, py);

                int s_begin = SEG * seg;
                int s_end   = min(s_begin + SEG + 1, NSAMP - 1);

                float tt = tparam(s_begin);
                float lx = fminf(fmaxf(p1x + tt * vx, 0.f), 2047.f);
                float ly = fminf(fmaxf(p1y + tt * vy, 0.f), 2047.f);
                float v_im1 = bilinV(V, lx, ly);
                tt = tparam(s_begin + 1);
                lx = fminf(fmaxf(p1x + tt * vx, 0.f), 2047.f);
                ly = fminf(fmaxf(p1y + tt * vy, 0.f), 2047.f);
                float v_i = bilinV(V, lx, ly);
                float cx = lx, cy = ly;

                float best_d2  = INFINITY;
                float best_idx = 1.0e9f;
                float best_val = 0.f;
                if (seg == 0) {     // default: argmin(all-inf)==0 -> vals[1]
                    best_idx = 0.f;
                    best_val = v_i;
                }

                #pragma unroll 5
                for (int s = s_begin + 2; s <= s_end; ++s) {
                    float ts = tparam(s);
                    float nlx = fminf(fmaxf(p1x + ts * vx, 0.f), 2047.f);
                    float nly = fminf(fmaxf(p1y + ts * vy, 0.f), 2047.f);
                    float v_ip1 = bilinV(V, nlx, nly);
                    if (v_i < v_im1 && v_i < v_ip1) {
                        float ex = cx - px, ey = cy - py;
                        float d2 = ex * ex + ey * ey;
                        if (d2 < best_d2) { best_d2 = d2; best_idx = (float)(s - 1); best_val = v_i; }
                    }
                    v_im1 = v_i; v_i = v_ip1; cx = nlx; cy = nly;
                }
                rec[e] = make_float4(best_d2, best_idx, best_val, ref_val);
            }
        }
    }
}

// ---------- reduce: combine 4 records per point (R8-verified), mean ----------
__global__ __launch_bounds__(256) void reduce_kernel(const float4* __restrict__ rec,
                                                     double* __restrict__ accum,
                                                     unsigned int* __restrict__ done,
                                                     float* __restrict__ out,
                                                     int N, int nblocks) {
    int i = blockIdx.x * blockDim.x + threadIdx.x;
    float sq = 0.f;
    if (i < N) {
        float4 best = rec[4 * i];
        float ref = best.w;
        #pragma unroll
        for (int k = 1; k < NSEG; ++k) {
            float4 r = rec[4 * i + k];
            if (r.x < best.x || (r.x == best.x && r.y < best.y)) best = r;
        }
        float diff = best.z - ref;
        sq = diff * diff;
    }
    for (int off = 32; off > 0; off >>= 1)
        sq += __shfl_down(sq, off);
    __shared__ float wsum[4];
    int lane = threadIdx.x & 63;
    int wid  = threadIdx.x >> 6;
    if (lane == 0) wsum[wid] = sq;
    __syncthreads();
    if (threadIdx.x == 0) {
        float bs = wsum[0] + wsum[1] + wsum[2] + wsum[3];
        atomicAdd(accum, (double)bs);
        __threadfence();
        unsigned int prev = atomicAdd(done, 1u);
        if (prev == (unsigned int)(nblocks - 1)) {
            double total = atomicAdd(accum, 0.0);
            out[0] = (float)(total / (double)N);
        }
    }
}

extern "C" void kernel_launch(void* const* d_in, const int* in_sizes, int n_in,
                              void* d_out, int out_size, void* d_ws, size_t ws_size,
                              hipStream_t stream) {
    const float* img     = (const float*)d_in[0];
    const float* points  = (const float*)d_in[1];
    const float* normals = (const float*)d_in[2];
    int N = in_sizes[1] / 2;
    float* out = (float*)d_out;

    // d_ws layout
    char* ws = (char*)d_ws;
    h2_t* V = (h2_t*)ws;
    size_t off = (size_t)IMG_W * IMG_H * sizeof(h2_t);          // 16 MiB
    double* accum        = (double*)(ws + off);       off += 8;
    unsigned int* done   = (unsigned int*)(ws + off); off += 8;
    unsigned int* qhead  = (unsigned int*)(ws + off); off += NREG * 4;
    unsigned int* qcnt   = (unsigned int*)(ws + off); off += NREG * 4;
    unsigned int* segoff = (unsigned int*)(ws + off); off += NREG * 4;
    unsigned int* cursor = (unsigned int*)(ws + off); off += NREG * 4;
    off = (off + 15) & ~(size_t)15;
    float4* pts4         = (float4*)(ws + off);       off += (size_t)N * 16;
    unsigned int* regs   = (unsigned int*)(ws + off); off += (size_t)N * 4;
    unsigned int* seglist= (unsigned int*)(ws + off); off += (size_t)N * NSEG * 4;
    off = (off + 15) & ~(size_t)15;
    float4* rec          = (float4*)(ws + off);                  // 4N float4

    zero_qcnt_kernel<<<1, 64, 0, stream>>>(qcnt);

    int conv_blocks = (IMG_W * IMG_H / 4) / 256;
    convert_bin_kernel<<<conv_blocks, 256, 0, stream>>>(img, V, points, normals,
                                                        pts4, regs, qcnt, accum, done, N);

    scan_kernel<<<1, 64, 0, stream>>>(qcnt, segoff, cursor, qhead);

    int pgrid = (N + 255) / 256;
    scatter_kernel<<<pgrid, 256, 0, stream>>>(regs, cursor, seglist, N);

    contour_seg_kernel<<<1024, 256, 0, stream>>>(V, pts4, seglist, segoff, qcnt, qhead, rec);

    reduce_kernel<<<pgrid, 256, 0, stream>>>(rec, accum, done, out, N, pgrid);
}

// Round 11
// 139.420 us; speedup vs baseline: 3.1332x; 3.1332x over previous
//
#include <hip/hip_runtime.h>
#include <float.h>
#include <math.h>

#define NSAMP 100
#define IMG_W 2048
#define IMG_H 2048
#define SEG 25          // centers per segment (R5/R8/R10-verified decomposition)
#define NSEG 4          // segments per point
#define NREG 8          // image regions = XCDs; tiles 512 wide x 1024 tall (4x2)

typedef _Float16 h2_t __attribute__((ext_vector_type(2), aligned(4)));
typedef _Float16 h4_t __attribute__((ext_vector_type(4), aligned(8)));
typedef _Float16 h8_t __attribute__((ext_vector_type(8), aligned(16)));

__device__ __forceinline__ float tparam(int s) {
    // matches np.linspace(0,1,100), bitwise-verified rounds 1-10
    return (s == NSAMP - 1) ? 1.0f : (float)((double)s * (1.0 / 99.0));
}

// Chord setup shared by bin and main (bitwise-identical formulas, R8/R10-verified).
__device__ __forceinline__ void chord(float px, float py, float nx, float ny,
                                      float& p1x, float& p1y, float& vx, float& vy) {
    float ddx = -ny, ddy = nx;
    float nrm = sqrtf(ddx * ddx + ddy * ddy);
    float dx = ddx / nrm, dy = ddy / nrm;
    const float maxf = FLT_MAX;
    float sdx = (dx != 0.f) ? dx : 1.f;
    float sdy = (dy != 0.f) ? dy : 1.f;
    float t_left   = (dx != 0.f) ? (0.f    - px) / sdx : -maxf;
    float t_right  = (dx != 0.f) ? (2047.f - px) / sdx :  maxf;
    float t_top    = (dy != 0.f) ? (0.f    - py) / sdy : -maxf;
    float t_bottom = (dy != 0.f) ? (2047.f - py) / sdy :  maxf;
    float t_min = fmaxf(t_left, t_top);
    float t_max = fminf(t_right, t_bottom);
    p1x = px + t_min * dx; p1y = py + t_min * dy;
    float p2x = px + t_max * dx, p2y = py + t_max * dy;
    vx = p2x - p1x; vy = p2y - p1y;
}

// tiny prologue: zero the 8 qcnt counters before convert_bin's atomics
__global__ void zero_qcnt_kernel(unsigned int* __restrict__ qcnt) {
    if (threadIdx.x < NREG) qcnt[threadIdx.x] = 0u;
}

// ---------- fused: V-texture build (R7-verified) + point binning (R8-verified) ----------
// NOTE: qcnt is zeroed ONLY by the prologue kernel; this kernel only accumulates
// (R10 had a racy in-kernel zero -- removed).
__global__ __launch_bounds__(256) void convert_bin_kernel(
        const float* __restrict__ in, h2_t* __restrict__ V,
        const float* __restrict__ points, const float* __restrict__ normals,
        float4* __restrict__ pts4, unsigned int* __restrict__ regs,
        unsigned int* __restrict__ qcnt,
        double* __restrict__ accum, unsigned int* __restrict__ done,
        int N) {
    __shared__ unsigned int lh[NREG];
    if (threadIdx.x < NREG) lh[threadIdx.x] = 0u;
    __syncthreads();
    int idx = blockIdx.x * blockDim.x + threadIdx.x;   // 1M threads
    if (idx == 0) { *accum = 0.0; *done = 0u; }

    // texture build
    {
        int y  = idx >> 9;          // row 0..2047
        int x4 = (idx & 511) << 2;  // col 0,4,..,2044
        int y1 = min(y + 1, IMG_H - 1);
        float4 a = *(const float4*)(in + (size_t)y  * IMG_W + x4);
        float4 b = *(const float4*)(in + (size_t)y1 * IMG_W + x4);
        h8_t o;
        o[0] = (_Float16)a.x; o[1] = (_Float16)b.x;
        o[2] = (_Float16)a.y; o[3] = (_Float16)b.y;
        o[4] = (_Float16)a.z; o[5] = (_Float16)b.z;
        o[6] = (_Float16)a.w; o[7] = (_Float16)b.w;
        *(h8_t*)(V + (size_t)y * IMG_W + x4) = o;
    }

    // point binning (first N threads)
    if (idx < N) {
        float px = fminf(fmaxf(points[2 * idx],     0.f), 2047.f);
        float py = fminf(fmaxf(points[2 * idx + 1], 0.f), 2047.f);
        float nx = normals[2 * idx];
        float ny = normals[2 * idx + 1];
        pts4[idx] = make_float4(px, py, nx, ny);
        float p1x, p1y, vx, vy;
        chord(px, py, nx, ny, p1x, p1y, vx, vy);
        unsigned int packed = 0;
        #pragma unroll
        for (int seg = 0; seg < NSEG; ++seg) {
            int s_begin = SEG * seg;
            int s_end   = min(s_begin + SEG + 1, NSAMP - 1);
            float f = (float)(s_begin + s_end) * 0.5f / 99.0f;
            float mx = fminf(fmaxf(p1x + f * vx, 0.f), 2047.f);
            float my = fminf(fmaxf(p1y + f * vy, 0.f), 2047.f);
            unsigned int r = ((unsigned int)my >> 10) * 4u + ((unsigned int)mx >> 9);
            packed |= r << (8 * seg);
            atomicAdd(&lh[r], 1u);
        }
        regs[idx] = packed;
    }
    __syncthreads();
    if (threadIdx.x < NREG && lh[threadIdx.x]) atomicAdd(&qcnt[threadIdx.x], lh[threadIdx.x]);
}

// ---------- scan: region offsets + scatter cursors ----------
__global__ void scan_kernel(const unsigned int* __restrict__ qcnt,
                            unsigned int* __restrict__ segoff,
                            unsigned int* __restrict__ cursor) {
    if (threadIdx.x == 0) {
        unsigned int run = 0;
        for (int r = 0; r < NREG; ++r) {
            segoff[r] = run;
            cursor[r] = run;
            run += qcnt[r];
        }
    }
}

// ---------- scatter: block-aggregated placement (R8/R10-verified) ----------
__global__ __launch_bounds__(256) void scatter_kernel(const unsigned int* __restrict__ regs,
                                                      unsigned int* __restrict__ cursor,
                                                      unsigned int* __restrict__ seglist,
                                                      int N) {
    __shared__ unsigned int lh[NREG];
    __shared__ unsigned int lbase[NREG];
    if (threadIdx.x < NREG) lh[threadIdx.x] = 0u;
    __syncthreads();
    int i = blockIdx.x * blockDim.x + threadIdx.x;
    unsigned int packed = 0, rank[NSEG];
    if (i < N) {
        packed = regs[i];
        #pragma unroll
        for (int seg = 0; seg < NSEG; ++seg) {
            unsigned int r = (packed >> (8 * seg)) & 0xFFu;
            rank[seg] = atomicAdd(&lh[r], 1u);
        }
    }
    __syncthreads();
    if (threadIdx.x < NREG)
        lbase[threadIdx.x] = lh[threadIdx.x] ? atomicAdd(&cursor[threadIdx.x], lh[threadIdx.x]) : 0u;
    __syncthreads();
    if (i < N) {
        #pragma unroll
        for (int seg = 0; seg < NSEG; ++seg) {
            unsigned int r = (packed >> (8 * seg)) & 0xFFu;
            seglist[lbase[r] + rank[seg]] = (unsigned int)(i * 4 + seg);
        }
    }
}

// ---------- bilinear via ONE 8-byte load (R7-verified) ----------
__device__ __forceinline__ float bilinV(const h2_t* __restrict__ V, float x, float y) {
    float x0f = floorf(x), y0f = floorf(y);
    float wx = x - x0f, wy = y - y0f;
    int x0 = (int)x0f;
    int y0 = (int)y0f;
    int xa = min(x0, IMG_W - 2);
    bool edge = (x0 == IMG_W - 1);
    h4_t q = *(const h4_t*)(V + (size_t)y0 * IMG_W + xa);
    float v00 = edge ? (float)q[2] : (float)q[0];
    float v10 = edge ? (float)q[3] : (float)q[1];
    float v01 = (float)q[2];
    float v11 = (float)q[3];
    return v00 * (1.f - wx) * (1.f - wy) + v01 * wx * (1.f - wy)
         + v10 * (1.f - wx) * wy       + v11 * wx * wy;
}

// ---------- main: STATIC XCD-affine slices; zero atomics / polls / barriers ----------
// Grid = 2048 blocks = full co-residency (8 blocks/CU x 256 CU). Block b handles
// region (b & 7) -- matching round-robin block->XCD dispatch -- and slice (b >> 3)
// of that region's seglist. Pure arithmetic work assignment.
__global__ __launch_bounds__(256) void contour_seg_kernel(
        const h2_t* __restrict__ V,
        const float4* __restrict__ pts4,
        const unsigned int* __restrict__ seglist,
        const unsigned int* __restrict__ segoff,
        const unsigned int* __restrict__ qcnt,
        float4* __restrict__ rec) {
    unsigned int q     = (unsigned int)blockIdx.x & 7u;
    unsigned int slice = (unsigned int)blockIdx.x >> 3;   // 0..255
    unsigned int qn = qcnt[q];
    unsigned int qo = segoff[q];
    unsigned int per = (qn + 255u) >> 8;                  // ceil(qn/256)
    unsigned int jb = slice * per;
    unsigned int je = min(jb + per, qn);

    for (unsigned int j = jb + threadIdx.x; j < je; j += 256u) {
        unsigned int e = seglist[qo + j];
        int i   = (int)(e >> 2);
        int seg = (int)(e & 3u);
        float4 pt = pts4[i];
        float px = pt.x, py = pt.y;
        float p1x, p1y, vx, vy;
        chord(px, py, pt.z, pt.w, p1x, p1y, vx, vy);

        float ref_val = 0.f;
        if (seg == 0) ref_val = bilinV(V, px, py);

        int s_begin = SEG * seg;
        int s_end   = min(s_begin + SEG + 1, NSAMP - 1);

        float tt = tparam(s_begin);
        float lx = fminf(fmaxf(p1x + tt * vx, 0.f), 2047.f);
        float ly = fminf(fmaxf(p1y + tt * vy, 0.f), 2047.f);
        float v_im1 = bilinV(V, lx, ly);
        tt = tparam(s_begin + 1);
        lx = fminf(fmaxf(p1x + tt * vx, 0.f), 2047.f);
        ly = fminf(fmaxf(p1y + tt * vy, 0.f), 2047.f);
        float v_i = bilinV(V, lx, ly);
        float cx = lx, cy = ly;

        float best_d2  = INFINITY;
        float best_idx = 1.0e9f;
        float best_val = 0.f;
        if (seg == 0) {     // default: argmin(all-inf)==0 -> vals[1]
            best_idx = 0.f;
            best_val = v_i;
        }

        #pragma unroll 5
        for (int s = s_begin + 2; s <= s_end; ++s) {
            float ts = tparam(s);
            float nlx = fminf(fmaxf(p1x + ts * vx, 0.f), 2047.f);
            float nly = fminf(fmaxf(p1y + ts * vy, 0.f), 2047.f);
            float v_ip1 = bilinV(V, nlx, nly);
            if (v_i < v_im1 && v_i < v_ip1) {
                float ex = cx - px, ey = cy - py;
                float d2 = ex * ex + ey * ey;
                if (d2 < best_d2) { best_d2 = d2; best_idx = (float)(s - 1); best_val = v_i; }
            }
            v_im1 = v_i; v_i = v_ip1; cx = nlx; cy = nly;
        }
        rec[e] = make_float4(best_d2, best_idx, best_val, ref_val);
    }
}

// ---------- reduce: combine 4 records per point (R8/R10-verified), mean ----------
__global__ __launch_bounds__(256) void reduce_kernel(const float4* __restrict__ rec,
                                                     double* __restrict__ accum,
                                                     unsigned int* __restrict__ done,
                                                     float* __restrict__ out,
                                                     int N, int nblocks) {
    int i = blockIdx.x * blockDim.x + threadIdx.x;
    float sq = 0.f;
    if (i < N) {
        float4 best = rec[4 * i];
        float ref = best.w;
        #pragma unroll
        for (int k = 1; k < NSEG; ++k) {
            float4 r = rec[4 * i + k];
            if (r.x < best.x || (r.x == best.x && r.y < best.y)) best = r;
        }
        float diff = best.z - ref;
        sq = diff * diff;
    }
    for (int off = 32; off > 0; off >>= 1)
        sq += __shfl_down(sq, off);
    __shared__ float wsum[4];
    int lane = threadIdx.x & 63;
    int wid  = threadIdx.x >> 6;
    if (lane == 0) wsum[wid] = sq;
    __syncthreads();
    if (threadIdx.x == 0) {
        float bs = wsum[0] + wsum[1] + wsum[2] + wsum[3];
        atomicAdd(accum, (double)bs);
        __threadfence();
        unsigned int prev = atomicAdd(done, 1u);
        if (prev == (unsigned int)(nblocks - 1)) {
            double total = atomicAdd(accum, 0.0);
            out[0] = (float)(total / (double)N);
        }
    }
}

extern "C" void kernel_launch(void* const* d_in, const int* in_sizes, int n_in,
                              void* d_out, int out_size, void* d_ws, size_t ws_size,
                              hipStream_t stream) {
    const float* img     = (const float*)d_in[0];
    const float* points  = (const float*)d_in[1];
    const float* normals = (const float*)d_in[2];
    int N = in_sizes[1] / 2;
    float* out = (float*)d_out;

    // d_ws layout
    char* ws = (char*)d_ws;
    h2_t* V = (h2_t*)ws;
    size_t off = (size_t)IMG_W * IMG_H * sizeof(h2_t);          // 16 MiB
    double* accum        = (double*)(ws + off);       off += 8;
    unsigned int* done   = (unsigned int*)(ws + off); off += 8;
    unsigned int* qcnt   = (unsigned int*)(ws + off); off += NREG * 4;
    unsigned int* segoff = (unsigned int*)(ws + off); off += NREG * 4;
    unsigned int* cursor = (unsigned int*)(ws + off); off += NREG * 4;
    off = (off + 15) & ~(size_t)15;
    float4* pts4         = (float4*)(ws + off);       off += (size_t)N * 16;
    unsigned int* regs   = (unsigned int*)(ws + off); off += (size_t)N * 4;
    unsigned int* seglist= (unsigned int*)(ws + off); off += (size_t)N * NSEG * 4;
    off = (off + 15) & ~(size_t)15;
    float4* rec          = (float4*)(ws + off);                  // 4N float4

    zero_qcnt_kernel<<<1, 64, 0, stream>>>(qcnt);

    int conv_blocks = (IMG_W * IMG_H / 4) / 256;
    convert_bin_kernel<<<conv_blocks, 256, 0, stream>>>(img, V, points, normals,
                                                        pts4, regs, qcnt, accum, done, N);

    scan_kernel<<<1, 64, 0, stream>>>(qcnt, segoff, cursor);

    int pgrid = (N + 255) / 256;
    scatter_kernel<<<pgrid, 256, 0, stream>>>(regs, cursor, seglist, N);

    contour_seg_kernel<<<2048, 256, 0, stream>>>(V, pts4, seglist, segoff, qcnt, rec);

    reduce_kernel<<<pgrid, 256, 0, stream>>>(rec, accum, done, out, N, pgrid);
}